// Round 8
// baseline (431.818 us; speedup 1.0000x reference)
//
#include <hip/hip_runtime.h>
#include <math.h>

#define H 128
#define IN 2048
#define PROJ 64
#define BT 32768      // B*T rows of x
#define T_STEPS 512
#define BATCH 64
#define BM 128
#define BKA 64

using f32x4  = __attribute__((ext_vector_type(4))) float;
using bfrag  = __attribute__((ext_vector_type(8))) short;   // 8 bf16
using h2_t   = __attribute__((ext_vector_type(2))) _Float16;

// v_cvt_pk_bf16_f32: d.lo = bf16(lo), d.hi = bf16(hi)  (RNE)
__device__ __forceinline__ unsigned cvtpk(float lo, float hi) {
  unsigned r;
  asm("v_cvt_pk_bf16_f32 %0, %1, %2" : "=v"(r) : "v"(lo), "v"(hi));
  return r;
}

// ---------------------------------------------------------------------------
// Kernel A: xp1[BT][H] = x[BT][IN] @ W_ih1^T + (b_ih1+b_hh1), bf16 MFMA.
// 256 blocks x 512 thr (8 waves, 2Mx4N). Tile 128(M) x 128(N=H) x 64(K).
// Reg-staged 1-deep pipeline, one barrier per chunk, XOR-swizzled LDS.
// ~60 us, near the 268 MB / 6.3 TB/s HBM floor. UNCHANGED.
// ---------------------------------------------------------------------------
__global__ __launch_bounds__(512) void xp1_gemm(
    const float* __restrict__ x, const float* __restrict__ W,
    const float* __restrict__ b1, const float* __restrict__ b2,
    float* __restrict__ xp1) {
  __shared__ __align__(16) char As[2][BM * BKA * 2];   // 2 x 16 KB
  __shared__ __align__(16) char Bs[2][H * BKA * 2];    // 2 x 16 KB
  const int t  = threadIdx.x;
  const int m0 = blockIdx.x * BM;
  const int wv = t >> 6, l = t & 63;
  const int wm = wv >> 2;
  const int wn = wv & 3;
  const int lr = l & 15;
  const int lq = l >> 4;

  const float* xg[4];
  const float* wg[4];
  int so[4];
#pragma unroll
  for (int i = 0; i < 4; ++i) {
    int c = t + 512 * i, r = c >> 4, k4 = c & 15;
    xg[i] = x + (size_t)(m0 + r) * IN + k4 * 4;
    wg[i] = W + (size_t)r * IN + k4 * 4;
    so[i] = (r * 128 + k4 * 8) ^ ((r & 7) << 4);
  }
  int ao[2][4], bo[2][2];
#pragma unroll
  for (int kf = 0; kf < 2; ++kf) {
#pragma unroll
    for (int mf = 0; mf < 4; ++mf) {
      int r = wm * 64 + mf * 16 + lr;
      ao[kf][mf] = (r * 128 + kf * 64 + lq * 16) ^ ((r & 7) << 4);
    }
#pragma unroll
    for (int nf = 0; nf < 2; ++nf) {
      int r = wn * 32 + nf * 16 + lr;
      bo[kf][nf] = (r * 128 + kf * 64 + lq * 16) ^ ((r & 7) << 4);
    }
  }

  f32x4 acc[4][2];
#pragma unroll
  for (int mf = 0; mf < 4; ++mf)
#pragma unroll
    for (int nf = 0; nf < 2; ++nf)
#pragma unroll
      for (int j = 0; j < 4; ++j) acc[mf][nf][j] = 0.f;

  float4 xr[4], wr[4];
#pragma unroll
  for (int i = 0; i < 4; ++i) {
    xr[i] = *(const float4*)&xg[i][0];
    wr[i] = *(const float4*)&wg[i][0];
  }
#pragma unroll
  for (int i = 0; i < 4; ++i) {
    uint2 ux; ux.x = cvtpk(xr[i].x, xr[i].y); ux.y = cvtpk(xr[i].z, xr[i].w);
    *(uint2*)(As[0] + so[i]) = ux;
    uint2 uw; uw.x = cvtpk(wr[i].x, wr[i].y); uw.y = cvtpk(wr[i].z, wr[i].w);
    *(uint2*)(Bs[0] + so[i]) = uw;
  }
  __syncthreads();

  for (int tc = 0; tc < 32; ++tc) {
    const int kc = (tc + 1) * BKA;
    if (tc < 31) {
#pragma unroll
      for (int i = 0; i < 4; ++i) {
        xr[i] = *(const float4*)&xg[i][kc];
        wr[i] = *(const float4*)&wg[i][kc];
      }
    }
    const char* Ab = As[tc & 1];
    const char* Bb = Bs[tc & 1];
#pragma unroll
    for (int kf = 0; kf < 2; ++kf) {
      bfrag af[4], bf[2];
#pragma unroll
      for (int mf = 0; mf < 4; ++mf) af[mf] = *(const bfrag*)(Ab + ao[kf][mf]);
#pragma unroll
      for (int nf = 0; nf < 2; ++nf) bf[nf] = *(const bfrag*)(Bb + bo[kf][nf]);
#pragma unroll
      for (int mf = 0; mf < 4; ++mf)
#pragma unroll
        for (int nf = 0; nf < 2; ++nf)
          acc[mf][nf] = __builtin_amdgcn_mfma_f32_16x16x32_bf16(
              af[mf], bf[nf], acc[mf][nf], 0, 0, 0);
    }
    if (tc < 31) {
      char* Aw = As[(tc + 1) & 1];
      char* Bw = Bs[(tc + 1) & 1];
#pragma unroll
      for (int i = 0; i < 4; ++i) {
        uint2 ux; ux.x = cvtpk(xr[i].x, xr[i].y); ux.y = cvtpk(xr[i].z, xr[i].w);
        *(uint2*)(Aw + so[i]) = ux;
        uint2 uw; uw.x = cvtpk(wr[i].x, wr[i].y); uw.y = cvtpk(wr[i].z, wr[i].w);
        *(uint2*)(Bw + so[i]) = uw;
      }
    }
    __syncthreads();
  }

  // epilogue: C/D layout col = lane&15, row = (lane>>4)*4 + j   [m89]
#pragma unroll
  for (int nf = 0; nf < 2; ++nf) {
    int n = wn * 32 + nf * 16 + lr;
    float bias = b1[n] + b2[n];
#pragma unroll
    for (int mf = 0; mf < 4; ++mf) {
      int mr = m0 + wm * 64 + mf * 16 + lq * 4;
#pragma unroll
      for (int j = 0; j < 4; ++j)
        xp1[(size_t)(mr + j) * H + n] = acc[mf][nf][j] + bias;
    }
  }
}

// ---------------------------------------------------------------------------
// Kernel B: fused 2-layer tanh RNN, skewed single-phase, RE-TILED: 256 thr
// (4 waves, 1 wave/SIMD). Thread (w=t>>6, g, q) owns rows 32w+g+8m (m=0..3)
// and k-octant [16q,16q+16). LDS h-read instrs halve (shared across the 4
// rows); ILP comes from 12 independent dot chains + 8 red8/tanh chains.
// Weights: 12 Wrow (96 VGPR) via non-remat asm loads, per-row vmcnt(0) +
// sched_barrier(0) (lesson #18: packs must not hoist above the wait).
// ---------------------------------------------------------------------------
struct Wrow { unsigned p0, p1, p2, p3, p4, p5, p6, p7; };  // 16 f16 = 8 h2

__device__ __forceinline__ unsigned pkh(float x, float y) {
  h2_t p = {(_Float16)x, (_Float16)y};
  return __builtin_bit_cast(unsigned, p);
}

__device__ __forceinline__ Wrow packrow(float4 a, float4 b, float4 c,
                                        float4 d) {
  Wrow w = {pkh(a.x, a.y), pkh(a.z, a.w), pkh(b.x, b.y), pkh(b.z, b.w),
            pkh(c.x, c.y), pkh(c.z, c.w), pkh(d.x, d.y), pkh(d.z, d.w)};
  return w;
}

// 64B row load: 4 non-remat asm loads + explicit wait + sched fence, then pack
__device__ __forceinline__ Wrow loadrow_safe(const float* p) {
  float4 a, b, c, d;
  asm volatile(
      "global_load_dwordx4 %0, %4, off\n\t"
      "global_load_dwordx4 %1, %5, off\n\t"
      "global_load_dwordx4 %2, %6, off\n\t"
      "global_load_dwordx4 %3, %7, off\n\t"
      "s_waitcnt vmcnt(0)"
      : "=&v"(a), "=&v"(b), "=&v"(c), "=&v"(d)
      : "v"(p), "v"(p + 4), "v"(p + 8), "v"(p + 12)
      : "memory");
  __builtin_amdgcn_sched_barrier(0);
  return packrow(a, b, c, d);
}

__device__ __forceinline__ float d2(unsigned w, int h, float acc) {
  return __builtin_amdgcn_fdot2(__builtin_bit_cast(h2_t, w),
                                __builtin_bit_cast(h2_t, (unsigned)h), acc,
                                false);
}

__device__ __forceinline__ float dot16(Wrow w, int4 lo, int4 hi, float acc) {
  acc = d2(w.p0, lo.x, acc);
  acc = d2(w.p1, lo.y, acc);
  acc = d2(w.p2, lo.z, acc);
  acc = d2(w.p3, lo.w, acc);
  acc = d2(w.p4, hi.x, acc);
  acc = d2(w.p5, hi.y, acc);
  acc = d2(w.p6, hi.z, acc);
  acc = d2(w.p7, hi.w, acc);
  return acc;
}

template <int CTRL>
__device__ __forceinline__ float dpp_add(float x) {
  return x + __builtin_bit_cast(
                 float, __builtin_amdgcn_mov_dpp(__builtin_bit_cast(int, x),
                                                 CTRL, 0xf, 0xf, true));
}

__device__ __forceinline__ float red8(float v) {
  v = dpp_add<0xB1>(v);    // quad_perm [1,0,3,2]  (+ lane^1)
  v = dpp_add<0x4E>(v);    // quad_perm [2,3,0,1]  (+ lane^2)
  v = dpp_add<0x141>(v);   // row_half_mirror      (+ other quad of 8-group)
  return v;
}

__device__ __forceinline__ float fast_tanh(float x) {
  float e = __expf(2.0f * x);
  return 1.0f - 2.0f / (e + 1.0f);
}

__global__ __launch_bounds__(256)
__attribute__((amdgpu_waves_per_eu(1, 1)))
void rnn_fused(
    const float* __restrict__ xp1,
    const float* __restrict__ W_hh1, const float* __restrict__ W_ih2,
    const float* __restrict__ W_hh2, const float* __restrict__ b_ih2,
    const float* __restrict__ b_hh2, const float* __restrict__ W_proj,
    const float* __restrict__ b_proj, const float* __restrict__ gamma,
    const float* __restrict__ beta, float* __restrict__ out) {
  __shared__ __align__(16) _Float16 h1s[2][H];
  __shared__ __align__(16) _Float16 h2s[2][H];
  const int t = threadIdx.x;
  const int b = blockIdx.x;
  const int l = t & 63;
  const int w = t >> 6;          // wave 0..3
  const int g = (l >> 3) & 7;
  const int q = l & 7;

  // rows owned: 32w + g + 8m, m = 0..3
  Wrow W1[4], W2[4], W3[4];
  float bias2[4];
  const float* xpr[4];
#pragma unroll
  for (int m = 0; m < 4; ++m) {
    const int r = 32 * w + g + 8 * m;
    W1[m] = loadrow_safe(&W_hh1[r * H + 16 * q]);
    W2[m] = loadrow_safe(&W_ih2[r * H + 16 * q]);
    W3[m] = loadrow_safe(&W_hh2[r * H + 16 * q]);
    bias2[m] = b_ih2[r] + b_hh2[r];
    xpr[m] = xpr[0];  // overwritten below; keeps array fully initialized
  }
#pragma unroll
  for (int m = 0; m < 4; ++m) {
    const int r = 32 * w + g + 8 * m;
    xpr[m] = xp1 + (size_t)b * T_STEPS * H + r;
  }

  // h1[-1], h2[-1] live in buffer parity (-1)&1 == 1
  if (t < H) { h1s[1][t] = (_Float16)0.f; h2s[1][t] = (_Float16)0.f; }
  __syncthreads();

  // peel i = 0: h1[0] = tanh(xp[0]); no h2 yet
  if (q == 0) {
#pragma unroll
    for (int m = 0; m < 4; ++m) {
      const int r = 32 * w + g + 8 * m;
      h1s[0][r] = (_Float16)fast_tanh(xpr[m][0]);
    }
  }
  __syncthreads();

  float xpc[4];
#pragma unroll
  for (int m = 0; m < 4; ++m) xpc[m] = xpr[m][H];   // xp[1]

  for (int i = 1; i < T_STEPS; ++i) {
    const _Float16* h1p = h1s[(i - 1) & 1];   // h1[i-1]
    const _Float16* h2p = h2s[i & 1];         // h2[i-2]
    _Float16* h1w = h1s[i & 1];               // h1[i]
    _Float16* h2w = h2s[(i - 1) & 1];         // h2[i-1]

    float nx[4];
#pragma unroll
    for (int m = 0; m < 4; ++m)
      nx[m] = (i + 1 < T_STEPS) ? xpr[m][(size_t)(i + 1) * H] : 0.f;

    int4 l1 = *(const int4*)&h1p[16 * q];     // h1[i-1] (feeds W1 and W2)
    int4 u1 = *(const int4*)&h1p[16 * q + 8];
    int4 l2 = *(const int4*)&h2p[16 * q];     // h2[i-2]
    int4 u2 = *(const int4*)&h2p[16 * q + 8];

    float a[4], bb[4];
#pragma unroll
    for (int m = 0; m < 4; ++m) {
      a[m] = dot16(W1[m], l1, u1, 0.f);       // W_hh1 . h1[i-1]
      float c = dot16(W3[m], l2, u2, 0.f);    // W_hh2 . h2[i-2]
      bb[m] = dot16(W2[m], l1, u1, c);        // W_ih2 . h1[i-1] + c
    }
#pragma unroll
    for (int m = 0; m < 4; ++m) { a[m] = red8(a[m]); bb[m] = red8(bb[m]); }

    if (q == 0) {
#pragma unroll
      for (int m = 0; m < 4; ++m) {
        const int r = 32 * w + g + 8 * m;
        h1w[r] = (_Float16)fast_tanh(xpc[m] + a[m]);     // h1[i]
        h2w[r] = (_Float16)fast_tanh(bias2[m] + bb[m]);  // h2[i-1]
      }
    }
    __syncthreads();                          // the ONLY barrier per step
#pragma unroll
    for (int m = 0; m < 4; ++m) xpc[m] = nx[m];
  }

  // peel i = T: h2[T-1] = tanh(bias2 + W_ih2.h1[T-1] + W_hh2.h2[T-2])
  {
    const _Float16* h1p = h1s[(T_STEPS - 1) & 1];   // h1s[1]: h1[T-1]
    const _Float16* h2p = h2s[T_STEPS & 1];         // h2s[0]: h2[T-2]
    _Float16* h2w = h2s[(T_STEPS - 1) & 1];         // h2s[1]: h2[T-1]
    int4 l1 = *(const int4*)&h1p[16 * q];
    int4 u1 = *(const int4*)&h1p[16 * q + 8];
    int4 l2 = *(const int4*)&h2p[16 * q];
    int4 u2 = *(const int4*)&h2p[16 * q + 8];
    float bb[4];
#pragma unroll
    for (int m = 0; m < 4; ++m) {
      float c = dot16(W3[m], l2, u2, 0.f);
      bb[m] = dot16(W2[m], l1, u1, c);
      bb[m] = red8(bb[m]);
    }
    if (q == 0) {
#pragma unroll
      for (int m = 0; m < 4; ++m) {
        const int r = 32 * w + g + 8 * m;
        h2w[r] = (_Float16)fast_tanh(bias2[m] + bb[m]);
      }
    }
    __syncthreads();
  }

  // projection + LayerNorm on h2s[1]; lanes 0..63 == wave 0 exactly
  if (t < PROJ) {
    const float* wp = W_proj + t * H;
    float z = b_proj[t];
#pragma unroll
    for (int i = 0; i < 32; ++i) {
      float4 wv = *(const float4*)&wp[4 * i];
      z = fmaf(wv.x, (float)h2s[1][4 * i + 0], z);
      z = fmaf(wv.y, (float)h2s[1][4 * i + 1], z);
      z = fmaf(wv.z, (float)h2s[1][4 * i + 2], z);
      z = fmaf(wv.w, (float)h2s[1][4 * i + 3], z);
    }
    float s = z;
#pragma unroll
    for (int d = 1; d < 64; d <<= 1) s += __shfl_xor(s, d);
    float mu = s * 0.015625f;
    float dz = z - mu;
    float v = dz * dz;
#pragma unroll
    for (int d = 1; d < 64; d <<= 1) v += __shfl_xor(v, d);
    float rstd = rsqrtf(v * 0.015625f + 1e-5f);
    out[b * PROJ + t] = dz * rstd * gamma[t] + beta[t];
  }
}

extern "C" void kernel_launch(void* const* d_in, const int* in_sizes, int n_in,
                              void* d_out, int out_size, void* d_ws, size_t ws_size,
                              hipStream_t stream) {
  const float* x      = (const float*)d_in[0];
  const float* W_ih1  = (const float*)d_in[1];
  const float* W_hh1  = (const float*)d_in[2];
  const float* b_ih1  = (const float*)d_in[3];
  const float* b_hh1  = (const float*)d_in[4];
  const float* W_ih2  = (const float*)d_in[5];
  const float* W_hh2  = (const float*)d_in[6];
  const float* b_ih2  = (const float*)d_in[7];
  const float* b_hh2  = (const float*)d_in[8];
  const float* W_proj = (const float*)d_in[9];
  const float* b_proj = (const float*)d_in[10];
  const float* gamma  = (const float*)d_in[11];
  const float* beta   = (const float*)d_in[12];

  float* xp1 = (float*)d_ws;   // BT*H*4 = 16 MB scratch

  xp1_gemm<<<BT / BM, 512, 0, stream>>>(x, W_ih1, b_ih1, b_hh1, xp1);
  rnn_fused<<<BATCH, 256, 0, stream>>>(xp1, W_hh1, W_ih2, W_hh2, b_ih2, b_hh2,
                                       W_proj, b_proj, gamma, beta,
                                       (float*)d_out);
}